// Round 1
// baseline (368.103 us; speedup 1.0000x reference)
//
#include <hip/hip_runtime.h>

#define NN 25000
#define NE 400000
#define CH 128
#define ECH 64
#define KTOT 320     // 2*CH + ECH
#define KPAD 328     // +8 halves pad -> row stride 656B, 16B aligned, spreads banks
#define BE 64        // edges per block

typedef _Float16 half8 __attribute__((ext_vector_type(8)));
typedef _Float16 half4v __attribute__((ext_vector_type(4)));
typedef float f32x4 __attribute__((ext_vector_type(4)));

// ---- kernel 1: out = x (fp32 copy), xh = fp16(x) ----
__global__ __launch_bounds__(256) void prep_kernel(const float* __restrict__ x,
                                                   float* __restrict__ out,
                                                   _Float16* __restrict__ xh) {
    int i = blockIdx.x * 256 + threadIdx.x;   // unit of 4 floats; grid covers exactly 3.2M
    float4 v = ((const float4*)x)[i];
    ((float4*)out)[i] = v;
    half4v h;
    h[0] = (_Float16)v.x; h[1] = (_Float16)v.y;
    h[2] = (_Float16)v.z; h[3] = (_Float16)v.w;
    ((half4v*)xh)[i] = h;
}

// ---- kernel 2: pack W (gate ++ msg) into MFMA B-fragment order, fp16 ----
// Wp flat index t = (((gct*10 + ks)*64 + lane)*8 + i), gct = w*4+ct
// B[k][n]: n (col) = ct*16 + (lane&15) within wave slice; k = ks*32 + 8*(lane>>4) + i
// wave w, ct in {0,1} -> gate channels 32w+(ct&1)*16+(l&15); ct in {2,3} -> msg, same chans
__global__ __launch_bounds__(256) void packw_kernel(const float* __restrict__ gw,
                                                    const float* __restrict__ mw,
                                                    _Float16* __restrict__ wp) {
    int t = blockIdx.x * 256 + threadIdx.x;   // 81920 total
    int i    = t & 7;
    int lane = (t >> 3) & 63;
    int ks   = (t >> 9) % 10;
    int gct  = t / 5120;          // 0..15
    int w  = gct >> 2, ct = gct & 3;
    int ch = w * 32 + (ct & 1) * 16 + (lane & 15);
    int k  = ks * 32 + 8 * (lane >> 4) + i;
    const float* src = (ct < 2) ? gw : mw;
    wp[t] = (_Float16)src[ch * KTOT + k];
}

// ---- kernel 3: main fused edge GEMM + activations + scatter-add ----
__global__ __launch_bounds__(256) void cgconv_kernel(const _Float16* __restrict__ xh,
                                                     const int* __restrict__ eidx,
                                                     const float* __restrict__ eattr,
                                                     const _Float16* __restrict__ wp,
                                                     const float* __restrict__ gate_b,
                                                     const float* __restrict__ msg_b,
                                                     float* __restrict__ out) {
    __shared__ _Float16 Z[BE][KPAD];
    __shared__ int rowI[BE];
    __shared__ int colI[BE];

    int tid = threadIdx.x;
    int e0  = blockIdx.x * BE;    // NE % BE == 0, no tail

    if (tid < BE) {
        rowI[tid] = eidx[e0 + tid];
        colI[tid] = eidx[NE + e0 + tid];
    }
    __syncthreads();

    // stage x[row] -> Z[:, 0:128)
    #pragma unroll
    for (int it = 0; it < 4; ++it) {
        int idx = it * 256 + tid;           // 1024 chunks of 8 halves
        int e = idx >> 4, c = idx & 15;
        int r = rowI[e];
        *(half8*)&Z[e][c * 8] = *(const half8*)&xh[(size_t)r * CH + c * 8];
    }
    // stage x[col] -> Z[:, 128:256)
    #pragma unroll
    for (int it = 0; it < 4; ++it) {
        int idx = it * 256 + tid;
        int e = idx >> 4, c = idx & 15;
        int r = colI[e];
        *(half8*)&Z[e][CH + c * 8] = *(const half8*)&xh[(size_t)r * CH + c * 8];
    }
    // stage edge_attr (fp32 -> fp16) -> Z[:, 256:320)
    #pragma unroll
    for (int it = 0; it < 2; ++it) {
        int idx = it * 256 + tid;           // 512 chunks of 8 floats
        int e = idx >> 3, c = idx & 7;
        const float4* p = (const float4*)&eattr[(size_t)(e0 + e) * ECH + c * 8];
        float4 v0 = p[0], v1 = p[1];
        half8 h;
        h[0] = (_Float16)v0.x; h[1] = (_Float16)v0.y; h[2] = (_Float16)v0.z; h[3] = (_Float16)v0.w;
        h[4] = (_Float16)v1.x; h[5] = (_Float16)v1.y; h[6] = (_Float16)v1.z; h[7] = (_Float16)v1.w;
        *(half8*)&Z[e][2 * CH + c * 8] = h;
    }
    __syncthreads();

    int lane = tid & 63;
    int w    = tid >> 6;          // wave id: owns channels [32w, 32w+32)
    int l15  = lane & 15;
    int lg   = lane >> 4;

    f32x4 acc[4][4];
    #pragma unroll
    for (int rt = 0; rt < 4; ++rt)
        #pragma unroll
        for (int ct = 0; ct < 4; ++ct) {
            acc[rt][ct][0] = 0.f; acc[rt][ct][1] = 0.f;
            acc[rt][ct][2] = 0.f; acc[rt][ct][3] = 0.f;
        }

    const half8* wpf = (const half8*)wp;
    #pragma unroll
    for (int ks = 0; ks < 10; ++ks) {
        half8 a[4], b[4];
        #pragma unroll
        for (int rt = 0; rt < 4; ++rt)
            a[rt] = *(const half8*)&Z[rt * 16 + l15][ks * 32 + 8 * lg];
        #pragma unroll
        for (int ct = 0; ct < 4; ++ct)
            b[ct] = wpf[(((w * 4 + ct) * 10) + ks) * 64 + lane];
        #pragma unroll
        for (int rt = 0; rt < 4; ++rt)
            #pragma unroll
            for (int ct = 0; ct < 4; ++ct)
                acc[rt][ct] = __builtin_amdgcn_mfma_f32_16x16x32_f16(a[rt], b[ct], acc[rt][ct], 0, 0, 0);
    }

    // epilogue: gate = sigmoid(acc_g + gb), cand = softplus(acc_m + mb), atomic scatter
    #pragma unroll
    for (int ct = 0; ct < 2; ++ct) {
        int ch = w * 32 + ct * 16 + l15;
        float gb = gate_b[ch];
        float mb = msg_b[ch];
        #pragma unroll
        for (int rt = 0; rt < 4; ++rt) {
            #pragma unroll
            for (int r = 0; r < 4; ++r) {
                int le = rt * 16 + lg * 4 + r;     // local edge row (C layout: row=4*lg+reg)
                float gv = acc[rt][ct][r] + gb;
                float mv = acc[rt][ct + 2][r] + mb;
                float g  = 1.0f / (1.0f + __expf(-gv));
                float sp = (mv > 15.0f) ? mv : log1pf(__expf(mv));
                int   c  = colI[le];
                atomicAdd(&out[(size_t)c * CH + ch], g * sp);
            }
        }
    }
}

extern "C" void kernel_launch(void* const* d_in, const int* in_sizes, int n_in,
                              void* d_out, int out_size, void* d_ws, size_t ws_size,
                              hipStream_t stream) {
    const float* x      = (const float*)d_in[0];
    const int*   eidx   = (const int*)d_in[1];
    const float* eattr  = (const float*)d_in[2];
    const float* gate_w = (const float*)d_in[3];
    const float* gate_b = (const float*)d_in[4];
    const float* msg_w  = (const float*)d_in[5];
    const float* msg_b  = (const float*)d_in[6];
    float* out = (float*)d_out;

    _Float16* xh = (_Float16*)d_ws;                         // 25000*128*2 = 6.4 MB
    _Float16* wp = (_Float16*)((char*)d_ws + 6400000);      // 256*320*2   = 160 KB

    prep_kernel<<<3125, 256, 0, stream>>>(x, out, xh);      // 3.2M/ (256*4) blocks exact
    packw_kernel<<<320, 256, 0, stream>>>(gate_w, msg_w, wp);
    cgconv_kernel<<<NE / BE, 256, 0, stream>>>(xh, eidx, eattr, wp, gate_b, msg_b, out);
}

// Round 2
// 344.230 us; speedup vs baseline: 1.0694x; 1.0694x over previous
//
#include <hip/hip_runtime.h>

#define NN 25000
#define NE 400000
#define CH 128
#define ECH 64
#define KTOT 320     // 2*CH + ECH
#define KPAD 328     // +8 halves pad -> row stride 656B, 16B aligned, spreads banks
#define BE 64        // edges per block
#define NCHUNK 25    // ceil(NN/1024)

typedef _Float16 half8 __attribute__((ext_vector_type(8)));
typedef _Float16 half4v __attribute__((ext_vector_type(4)));
typedef float f32x4 __attribute__((ext_vector_type(4)));

// ---- kernel 1: out = x (fp32 copy), xh = fp16(x) ----
__global__ __launch_bounds__(256) void prep_kernel(const float* __restrict__ x,
                                                   float* __restrict__ out,
                                                   _Float16* __restrict__ xh) {
    int i = blockIdx.x * 256 + threadIdx.x;   // unit of 4 floats; grid covers exactly 3.2M
    float4 v = ((const float4*)x)[i];
    ((float4*)out)[i] = v;
    half4v h;
    h[0] = (_Float16)v.x; h[1] = (_Float16)v.y;
    h[2] = (_Float16)v.z; h[3] = (_Float16)v.w;
    ((half4v*)xh)[i] = h;
}

// ---- kernel 2: pack W (gate ++ msg) into MFMA B-fragment order, fp16 ----
__global__ __launch_bounds__(256) void packw_kernel(const float* __restrict__ gw,
                                                    const float* __restrict__ mw,
                                                    _Float16* __restrict__ wp) {
    int t = blockIdx.x * 256 + threadIdx.x;   // 81920 total
    int i    = t & 7;
    int lane = (t >> 3) & 63;
    int ks   = (t >> 9) % 10;
    int gct  = t / 5120;          // 0..15
    int w  = gct >> 2, ct = gct & 3;
    int ch = w * 32 + (ct & 1) * 16 + (lane & 15);
    int k  = ks * 32 + 8 * (lane >> 4) + i;
    const float* src = (ct < 2) ? gw : mw;
    wp[t] = (_Float16)src[ch * KTOT + k];
}

// ---- sort infra: zero, histogram, block scan, chunk scan, rank ----
__global__ __launch_bounds__(256) void zero_kernel(int* __restrict__ p, int n) {
    int i = blockIdx.x * 256 + threadIdx.x;
    if (i < n) p[i] = 0;
}

__global__ __launch_bounds__(256) void hist_kernel(const int* __restrict__ eidx,
                                                   int* __restrict__ cnt) {
    int i = blockIdx.x * 256 + threadIdx.x;
    if (i < NE) atomicAdd(&cnt[eidx[NE + i]], 1);
}

__global__ __launch_bounds__(1024) void scanA_kernel(const int* __restrict__ cnt,
                                                     int* __restrict__ offs,
                                                     int* __restrict__ tot) {
    __shared__ int buf[1024];
    int tid = threadIdx.x;
    int i = blockIdx.x * 1024 + tid;
    int v = (i < NN) ? cnt[i] : 0;
    buf[tid] = v;
    __syncthreads();
    for (int off = 1; off < 1024; off <<= 1) {
        int t = (tid >= off) ? buf[tid - off] : 0;
        __syncthreads();
        buf[tid] += t;
        __syncthreads();
    }
    if (i < NN) offs[i] = buf[tid] - v;           // exclusive within chunk
    if (tid == 1023) tot[blockIdx.x] = buf[1023]; // chunk total
}

__global__ void scanB_kernel(int* __restrict__ tot) {   // 1 block, 64 threads
    int lane = threadIdx.x;
    int v = (lane < NCHUNK) ? tot[lane] : 0;
    int orig = v;
    for (int off = 1; off < 32; off <<= 1) {
        int t = __shfl_up(v, off);
        if (lane >= off) v += t;
    }
    if (lane < NCHUNK) tot[lane] = v - orig;      // exclusive chunk bases
}

__global__ __launch_bounds__(256) void rank_kernel(const int* __restrict__ eidx,
                                                   const int* __restrict__ offs,
                                                   const int* __restrict__ tot,
                                                   int* __restrict__ cur,
                                                   int* __restrict__ perm) {
    int i = blockIdx.x * 256 + threadIdx.x;
    if (i < NE) {
        int c = eidx[NE + i];
        int p = offs[c] + tot[c >> 10] + atomicAdd(&cur[c], 1);
        perm[p] = i;
    }
}

// ---- main fused edge GEMM + activations + segmented scatter-add ----
__global__ __launch_bounds__(256) void cgconv_kernel(const _Float16* __restrict__ xh,
                                                     const int* __restrict__ eidx,
                                                     const float* __restrict__ eattr,
                                                     const _Float16* __restrict__ wp,
                                                     const int* __restrict__ perm,
                                                     const float* __restrict__ gate_b,
                                                     const float* __restrict__ msg_b,
                                                     float* __restrict__ out) {
    __shared__ __align__(16) char smem[BE * KPAD * 2];   // 41984 B; reused as M[64][128] f32
    __shared__ int rowI[BE];
    __shared__ int colI[BE];
    __shared__ int sI[BE];
    _Float16 (*Z)[KPAD] = (_Float16 (*)[KPAD])smem;
    float* M = (float*)smem;

    int tid = threadIdx.x;
    int e0  = blockIdx.x * BE;    // NE % BE == 0, no tail

    if (tid < BE) {
        int p = perm[e0 + tid];   // sorted-by-col edge ids
        sI[tid]   = p;
        rowI[tid] = eidx[p];
        colI[tid] = eidx[NE + p];
    }
    __syncthreads();

    // stage x[row] -> Z[:, 0:128)
    #pragma unroll
    for (int it = 0; it < 4; ++it) {
        int idx = it * 256 + tid;           // 1024 chunks of 8 halves
        int e = idx >> 4, c = idx & 15;
        int r = rowI[e];
        *(half8*)&Z[e][c * 8] = *(const half8*)&xh[(size_t)r * CH + c * 8];
    }
    // stage x[col] -> Z[:, 128:256)
    #pragma unroll
    for (int it = 0; it < 4; ++it) {
        int idx = it * 256 + tid;
        int e = idx >> 4, c = idx & 15;
        int r = colI[e];
        *(half8*)&Z[e][CH + c * 8] = *(const half8*)&xh[(size_t)r * CH + c * 8];
    }
    // stage edge_attr (fp32 -> fp16) -> Z[:, 256:320)
    #pragma unroll
    for (int it = 0; it < 2; ++it) {
        int idx = it * 256 + tid;           // 512 chunks of 8 floats
        int e = idx >> 3, c = idx & 7;
        const float4* p = (const float4*)&eattr[(size_t)sI[e] * ECH + c * 8];
        float4 v0 = p[0], v1 = p[1];
        half8 h;
        h[0] = (_Float16)v0.x; h[1] = (_Float16)v0.y; h[2] = (_Float16)v0.z; h[3] = (_Float16)v0.w;
        h[4] = (_Float16)v1.x; h[5] = (_Float16)v1.y; h[6] = (_Float16)v1.z; h[7] = (_Float16)v1.w;
        *(half8*)&Z[e][2 * CH + c * 8] = h;
    }
    __syncthreads();

    int lane = tid & 63;
    int w    = tid >> 6;          // wave id: owns channels [32w, 32w+32)
    int l15  = lane & 15;
    int lg   = lane >> 4;

    f32x4 acc[4][4];
    #pragma unroll
    for (int rt = 0; rt < 4; ++rt)
        #pragma unroll
        for (int ct = 0; ct < 4; ++ct) {
            acc[rt][ct][0] = 0.f; acc[rt][ct][1] = 0.f;
            acc[rt][ct][2] = 0.f; acc[rt][ct][3] = 0.f;
        }

    const half8* wpf = (const half8*)wp;
    #pragma unroll
    for (int ks = 0; ks < 10; ++ks) {
        half8 a[4], b[4];
        #pragma unroll
        for (int rt = 0; rt < 4; ++rt)
            a[rt] = *(const half8*)&Z[rt * 16 + l15][ks * 32 + 8 * lg];
        #pragma unroll
        for (int ct = 0; ct < 4; ++ct)
            b[ct] = wpf[(((w * 4 + ct) * 10) + ks) * 64 + lane];
        #pragma unroll
        for (int rt = 0; rt < 4; ++rt)
            #pragma unroll
            for (int ct = 0; ct < 4; ++ct)
                acc[rt][ct] = __builtin_amdgcn_mfma_f32_16x16x32_f16(a[rt], b[ct], acc[rt][ct], 0, 0, 0);
    }

    __syncthreads();   // all Z reads complete; smem is reused as M below

    // activations -> M[le][ch] (XOR-swizzled so the 4 lg-groups spread banks)
    #pragma unroll
    for (int ct = 0; ct < 2; ++ct) {
        int ch  = w * 32 + ct * 16 + l15;
        int chs = ch ^ (lg << 3);
        float gb = gate_b[ch];
        float mb = msg_b[ch];
        #pragma unroll
        for (int rt = 0; rt < 4; ++rt) {
            #pragma unroll
            for (int r = 0; r < 4; ++r) {
                int le = rt * 16 + lg * 4 + r;     // C layout: row = 4*lg + reg
                float gv = acc[rt][ct][r] + gb;
                float mv = acc[rt][ct + 2][r] + mb;
                float g  = __builtin_amdgcn_rcpf(1.0f + __expf(-gv));
                float sp = (mv > 15.0f) ? mv : __logf(1.0f + __expf(mv));
                M[le * CH + chs] = g * sp;
            }
        }
    }
    __syncthreads();

    // segmented walk over sorted cols: one atomic per (distinct col, channel)
    int ch2 = tid & 127;
    int h   = tid >> 7;           // two halves of 32 edges
    float a2 = 0.f;
    int prev = colI[h * 32];
    for (int i2 = 0; i2 < 32; ++i2) {
        int e = h * 32 + i2;
        int c = colI[e];
        float m = M[e * CH + (ch2 ^ (((e >> 2) & 3) << 3))];
        if (c != prev) {
            atomicAdd(&out[(size_t)prev * CH + ch2], a2);
            a2 = 0.f;
            prev = c;
        }
        a2 += m;
    }
    atomicAdd(&out[(size_t)prev * CH + ch2], a2);
}

extern "C" void kernel_launch(void* const* d_in, const int* in_sizes, int n_in,
                              void* d_out, int out_size, void* d_ws, size_t ws_size,
                              hipStream_t stream) {
    const float* x      = (const float*)d_in[0];
    const int*   eidx   = (const int*)d_in[1];
    const float* eattr  = (const float*)d_in[2];
    const float* gate_w = (const float*)d_in[3];
    const float* gate_b = (const float*)d_in[4];
    const float* msg_w  = (const float*)d_in[5];
    const float* msg_b  = (const float*)d_in[6];
    float* out = (float*)d_out;

    char* ws = (char*)d_ws;
    _Float16* xh  = (_Float16*)(ws);                 // 6,400,000 B
    _Float16* wp  = (_Float16*)(ws + 6400000);       //   163,840 B
    int* cnt  = (int*)(ws + 6563840);                //   100,096 B (25024 ints)
    int* cur  = (int*)(ws + 6663936);                //   100,096 B
    int* offs = (int*)(ws + 6764032);                //   100,096 B
    int* tot  = (int*)(ws + 6864128);                //       128 B
    int* perm = (int*)(ws + 6864256);                // 1,600,000 B  (ends at 8.46 MB)

    prep_kernel<<<3125, 256, 0, stream>>>(x, out, xh);
    packw_kernel<<<320, 256, 0, stream>>>(gate_w, msg_w, wp);
    zero_kernel<<<196, 256, 0, stream>>>(cnt, 50048);            // cnt + cur contiguous
    hist_kernel<<<1563, 256, 0, stream>>>(eidx, cnt);
    scanA_kernel<<<NCHUNK, 1024, 0, stream>>>(cnt, offs, tot);
    scanB_kernel<<<1, 64, 0, stream>>>(tot);
    rank_kernel<<<1563, 256, 0, stream>>>(eidx, offs, tot, cur, perm);
    cgconv_kernel<<<NE / BE, 256, 0, stream>>>(xh, eidx, eattr, wp, perm, gate_b, msg_b, out);
}